// Round 2
// baseline (57380.811 us; speedup 1.0000x reference)
//
#include <hip/hip_runtime.h>
#include <hip/hip_bf16.h>
#include <math.h>

typedef __attribute__((ext_vector_type(8))) short bf16x8;
typedef __attribute__((ext_vector_type(4))) float f32x4;

// ---- workspace byte offsets ----
#define B_X2    0u            // 512*32*256 bf16  = 8388608
#define B_PM    8388608u      // 32*256*128 f32   = 4194304
#define B_WSA   12582912u     // 4096*1792 bf16   = 14680064
#define B_WSD   27262976u     // 4096*2560 bf16   = 20971520
#define B_AHB0  48234496u     // 32*1024 bf16
#define B_AHB1  48300032u
#define B_DHB0  48365568u
#define B_DHB1  48431104u
#define B_CTXB  48496640u     // 32*512 bf16
#define B_AC    48529408u     // 32*1024 f32
#define B_DC    48660480u
#define B_AWC   48791552u     // 32*256 f32
#define B_ZERO_START 48234496u
#define B_ZERO_BYTES 589824u
#define B_AHF   48824320u     // 32*1024 f32
#define B_DHF0  48955392u     // 32*1024 f32
#define B_CTXF0 49086464u     // 32*512 f32
#define B_CTXF1 49152000u     // 32*512 f32
#define B_DHF1  49217536u     // 32*1024 f32
#define B_DONE  49348608u     // doneA 256 ints | doneC 32 ints

// ---- output offsets (floats) ----
#define OUT_MEL   0u
#define OUT_GATE  1310720u
#define OUT_ALIGN 1327104u

// ---- shared memory overlay (28 KB) ----
#define SM_BYTES 27392
// attn: locb @0 (20480), aw_s @20480, awc_s @21632, pq_s @22784,
//       red @23296 (2048), esh @25344, wgt_s @26368
// gemm: red @0 (16384), gsum @16384 (2176)
// proj: pi @0 (6144)

__device__ __forceinline__ float sigf(float x) { return 1.f / (1.f + expf(-x)); }
__device__ __forceinline__ float ftanh(float x) {
    float t = exp2f(x * 2.885390081777927f);
    return 1.f - 2.f * __builtin_amdgcn_rcpf(t + 1.f);
}

// ---- one-way flag protocol (agent scope, generation counters) ----
__device__ __forceinline__ void wait_flags(const int* f, int n, int target) {
    int lane = threadIdx.x & 63;
    for (;;) {
        bool ok = true;
        for (int i = lane; i < n; i += 64)
            ok &= (__hip_atomic_load(f + i, __ATOMIC_RELAXED,
                                     __HIP_MEMORY_SCOPE_AGENT) == target);
        if (__all(ok)) break;
        __builtin_amdgcn_s_sleep(16);
    }
    __builtin_amdgcn_fence(__ATOMIC_ACQUIRE, "agent");
}
__device__ __forceinline__ void release_flag(int* slot, int target) {
    __builtin_amdgcn_fence(__ATOMIC_RELEASE, "agent");
    __hip_atomic_store(slot, target, __ATOMIC_RELAXED, __HIP_MEMORY_SCOPE_AGENT);
}

// ============================================================
// Prenet for all timesteps -> bf16 x2[t][b][256]
// ============================================================
__global__ __launch_bounds__(256) void prenet_kernel(
    const float* __restrict__ dec_in,
    const float* __restrict__ w1,
    const float* __restrict__ w2,
    __hip_bfloat16* __restrict__ x2)
{
    int b  = blockIdx.x & 31;
    int t0 = (blockIdx.x >> 5) * 16;
    __shared__ float xin[16][80];
    __shared__ float h1[16][257];

    for (int i = threadIdx.x; i < 16 * 80; i += 256) {
        int tt = i / 80, m = i - tt * 80;
        int t = t0 + tt;
        xin[tt][m] = (t == 0) ? 0.f
                   : dec_in[(size_t)b * 80 * 512 + (size_t)m * 512 + (t - 1)];
    }
    __syncthreads();
    for (int i = threadIdx.x; i < 16 * 256; i += 256) {
        int tt = i >> 8, p = i & 255;
        const float* wr = w1 + p * 80;
        float s = 0.f;
        for (int m = 0; m < 80; ++m) s += xin[tt][m] * wr[m];
        h1[tt][p] = fmaxf(s, 0.f);
    }
    __syncthreads();
    for (int i = threadIdx.x; i < 16 * 256; i += 256) {
        int tt = i >> 8, q = i & 255;
        const float* wr = w2 + q * 256;
        float s = 0.f;
        for (int p = 0; p < 256; ++p) s += h1[tt][p] * wr[p];
        int t = t0 + tt;
        x2[(size_t)t * (32 * 256) + b * 256 + q] = __float2bfloat16(fmaxf(s, 0.f));
    }
}

// ============================================================
// processed_memory (f32)
// ============================================================
__global__ __launch_bounds__(128) void pm_kernel(
    const float* __restrict__ memory,
    const float* __restrict__ wm,
    float* __restrict__ pm)
{
    int b = blockIdx.y, tt0 = blockIdx.x * 16;
    __shared__ float ms[16][513];
    for (int i = threadIdx.x; i < 16 * 512; i += 128) {
        int tt = i >> 9, e = i & 511;
        ms[tt][e] = memory[(size_t)b * 131072 + (size_t)(tt0 + tt) * 512 + e];
    }
    __syncthreads();
    int d = threadIdx.x;
    float acc[16];
#pragma unroll
    for (int i = 0; i < 16; ++i) acc[i] = 0.f;
    const float* wr = wm + d * 512;
    for (int e = 0; e < 512; ++e) {
        float w = wr[e];
#pragma unroll
        for (int ttl = 0; ttl < 16; ++ttl) acc[ttl] += w * ms[ttl][e];
    }
    for (int ttl = 0; ttl < 16; ++ttl)
        pm[(size_t)b * 32768 + (size_t)(tt0 + ttl) * 128 + d] = acc[ttl];
}

// ============================================================
// Weight swizzle (unchanged)
// ============================================================
__global__ __launch_bounds__(256) void swizzle_kernel(
    const float* __restrict__ wih, int Kih,
    const float* __restrict__ whh, int Khh,
    __hip_bfloat16* __restrict__ out, int K)
{
    int idx = blockIdx.x * 256 + threadIdx.x;
    int lane = idx & 63;
    int tk = idx >> 6;
    int KB = K >> 5;
    int nt = tk / KB, kb = tk - nt * KB;
    int c = lane & 15;
    int n = (c >> 2) * 1024 + nt * 4 + (c & 3);
    int k = kb * 32 + ((lane >> 4) << 3);
    const float* src; int kk;
    if (k < Kih) { src = wih + (size_t)n * Kih; kk = k; }
    else         { src = whh + (size_t)n * Khh; kk = k - Kih; }
    __hip_bfloat16* op = out + (size_t)idx * 8;
#pragma unroll
    for (int j = 0; j < 8; ++j) op[j] = __float2bfloat16(src[kk + j]);
}

// ============================================================
// LSTM gates GEMM tile + epilogue (device fn, per-block role)
// ============================================================
template<int K, int S0, int S1, int S0STR, int S1STR, int S2STR, bool WAITA, bool WAITC>
__device__ __forceinline__ void lstm_tile(
    char* smem, int nt, int tgt,
    const __hip_bfloat16* __restrict__ seg0,
    const __hip_bfloat16* __restrict__ seg1,
    const __hip_bfloat16* __restrict__ seg2,
    const __hip_bfloat16* __restrict__ wsw,
    const float* __restrict__ bias,
    float* __restrict__ c_state,
    float* __restrict__ h_f32,
    __hip_bfloat16* __restrict__ h_bf16,
    const int* doneA, const int* doneC, int* relA)
{
    constexpr int KB  = K / 32;
    constexpr int NCH = K / 256;

    float (*red)[2][4][64] = (float(*)[2][4][64])smem;
    float (*gsum)[17]      = (float(*)[17])(smem + 16384);

    int tid  = threadIdx.x;
    int lane = tid & 63;
    int w    = tid >> 6;
    int r0   = lane & 15;
    int kq   = (lane >> 4) << 3;

    if (WAITA) wait_flags(doneA, 256, tgt);
    if (WAITC && (w == 3 || w == 4)) wait_flags(doneC, 32, tgt);

    const __hip_bfloat16* wp = wsw + (((size_t)nt * KB + (size_t)w * NCH) * 64 + lane) * 8;
    f32x4 acc0 = {0.f, 0.f, 0.f, 0.f};
    f32x4 acc1 = {0.f, 0.f, 0.f, 0.f};
    int k0 = w * (K / 8);

#pragma unroll
    for (int i = 0; i < NCH; ++i) {
        int kc = k0 + i * 32;
        const __hip_bfloat16* sp; int sstr, off;
        if (kc < S0)           { sp = seg0; sstr = S0STR; off = kc; }
        else if (kc < S0 + S1) { sp = seg1; sstr = S1STR; off = kc - S0; }
        else                   { sp = seg2; sstr = S2STR; off = kc - S0 - S1; }
        int ko = off + kq;
        bf16x8 a0 = *(const bf16x8*)(sp + (size_t)r0 * sstr + ko);
        bf16x8 a1 = *(const bf16x8*)(sp + (size_t)(r0 + 16) * sstr + ko);
        bf16x8 bb = *(const bf16x8*)(wp + (size_t)i * 512);
        acc0 = __builtin_amdgcn_mfma_f32_16x16x32_bf16(a0, bb, acc0, 0, 0, 0);
        acc1 = __builtin_amdgcn_mfma_f32_16x16x32_bf16(a1, bb, acc1, 0, 0, 0);
    }

#pragma unroll
    for (int r = 0; r < 4; ++r) {
        (*(&red[w]))[0][r][lane] = acc0[r];
        (*(&red[w]))[1][r][lane] = acc1[r];
    }
    __syncthreads();

    {
        int b = tid >> 4, c = tid & 15;
        int mt = b >> 4, bm = b & 15;
        int lidx = ((bm >> 2) << 4) + c, rg = bm & 3;
        float s = 0.f;
#pragma unroll
        for (int ks = 0; ks < 8; ++ks) s += red[ks][mt][rg][lidx];
        gsum[b][c] = s;
    }
    __syncthreads();

    if (tid < 128) {
        int b = tid & 31, jl = tid >> 5;
        int j = nt * 4 + jl;
        float gi = gsum[b][jl]      + bias[j];
        float gf = gsum[b][4 + jl]  + bias[1024 + j];
        float gg = gsum[b][8 + jl]  + bias[2048 + j];
        float go = gsum[b][12 + jl] + bias[3072 + j];
        float cv = c_state[b * 1024 + j];
        float c2 = sigf(gf) * cv + sigf(gi) * tanhf(gg);
        float h2 = sigf(go) * tanhf(c2);
        c_state[b * 1024 + j] = c2;
        h_f32[b * 1024 + j]   = h2;
        h_bf16[b * 1024 + j]  = __float2bfloat16(h2);
    }
    if (relA) {
        __syncthreads();
        if (tid == 0) release_flag(relA + nt, tgt);
    }
}

// ============================================================
// Mega step kernel: one launch per timestep.
// blocks [0,256)   : lstmA tiles         -> release doneA
// blocks [256,288) : attention (b)       -> wait doneA, release doneC
// blocks [288,544) : lstmD tiles         -> wait doneA (+doneC waves 3,4)
// blocks [544,576) : proj for t-1        (prev-launch data only)
// ============================================================
__global__ __launch_bounds__(512, 2) void step_kernel(
    const float* __restrict__ memory,
    const int*   __restrict__ mlen,
    const float* __restrict__ wq,
    const float* __restrict__ v,
    const float* __restrict__ lconv,
    const float* __restrict__ ldense,
    const float* __restrict__ pm,
    const __hip_bfloat16* __restrict__ x2b,
    const __hip_bfloat16* __restrict__ wswA,
    const __hip_bfloat16* __restrict__ wswD,
    const float* __restrict__ a_b,
    const float* __restrict__ d_b,
    float* __restrict__ ac,
    float* __restrict__ dc,
    float* __restrict__ ahf,
    __hip_bfloat16* __restrict__ ahb0,
    __hip_bfloat16* __restrict__ ahb1,
    __hip_bfloat16* __restrict__ dhb0,
    __hip_bfloat16* __restrict__ dhb1,
    __hip_bfloat16* __restrict__ ctxb,
    float* __restrict__ ctxf0,
    float* __restrict__ ctxf1,
    float* __restrict__ dhf0,
    float* __restrict__ dhf1,
    float* __restrict__ awc,
    float* __restrict__ align_out,
    float* __restrict__ out_mel,
    float* __restrict__ out_gate,
    const float* __restrict__ proj_w,
    const float* __restrict__ proj_b,
    const float* __restrict__ gate_w,
    const float* __restrict__ gate_b,
    int* __restrict__ doneA,
    int* __restrict__ doneC,
    int t)
{
    __shared__ char smem[SM_BYTES];
    int blk = blockIdx.x;
    int tid = threadIdx.x;

    __hip_bfloat16* ah_prev = (t & 1) ? ahb1 : ahb0;
    __hip_bfloat16* ah_cur  = (t & 1) ? ahb0 : ahb1;
    __hip_bfloat16* dh_prev = (t & 1) ? dhb1 : dhb0;
    __hip_bfloat16* dh_cur  = (t & 1) ? dhb0 : dhb1;
    float* ctxf_cur = (t & 1) ? ctxf1 : ctxf0;
    float* dhf_cur  = (t & 1) ? dhf1  : dhf0;

    if (blk < 256) {
        // ---------------- attention-LSTM GEMM ----------------
        lstm_tile<1792, 256, 512, 256, 512, 1024, false, false>(
            smem, blk, t + 1,
            x2b + (size_t)t * 8192, ctxb, ah_prev,
            wswA, a_b, ac, ahf, ah_cur, nullptr, nullptr, doneA);
        return;
    }

    if (blk < 288) {
        // ---------------- attention ----------------
        int b = blk - 256;
        __hip_bfloat16 (*locb)[40] = (__hip_bfloat16(*)[40])smem;
        float* aw_s  = (float*)(smem + 20480);
        float* awc_s = (float*)(smem + 21632);
        float* pq_s  = (float*)(smem + 22784);
        float* red   = (float*)(smem + 23296);
        float* esh   = (float*)(smem + 25344);
        float* wgt_s = (float*)(smem + 26368);

        int len = mlen[b];
        wait_flags(doneA, 256, t + 1);

        // phase A: stage aw/awc halo + pq partials
        if (tid < 288) {
            int tt = tid - 15;
            float a = 0.f, c = 0.f;
            if (tt >= 0 && tt < 256) {
                a = (t == 0) ? 0.f
                  : align_out[(size_t)b * 131072 + (size_t)(t - 1) * 256 + tt];
                c = awc[b * 256 + tt];
            }
            aw_s[tid] = a; awc_s[tid] = c;
        }
        {
            int d = tid >> 2, p = tid & 3;
            const float4* wr = (const float4*)(wq + (size_t)d * 1024 + p * 256);
            const float4* hr = (const float4*)(ahf + b * 1024 + p * 256);
            float s = 0.f;
#pragma unroll 8
            for (int k = 0; k < 64; ++k) {
                float4 a = wr[k], h4 = hr[k];
                s += a.x * h4.x + a.y * h4.y + a.z * h4.z + a.w * h4.w;
            }
            red[tid] = s;
        }
        __syncthreads();

        // phase B: pq reduce + location conv (2 items/thread)
        if (tid < 128)
            pq_s[tid] = red[tid * 4] + red[tid * 4 + 1]
                      + red[tid * 4 + 2] + red[tid * 4 + 3];
        for (int it = 0; it < 2; ++it) {
            int item = tid + it * 512;
            int f = item >> 5, ttg = item & 31;
            const float* kcA = lconv + f * 62;
            const float* kcB = kcA + 31;
            float ka[31], kb_[31];
#pragma unroll
            for (int k = 0; k < 31; ++k) { ka[k] = kcA[k]; kb_[k] = kcB[k]; }
            float acc[8];
#pragma unroll
            for (int s = 0; s < 8; ++s) acc[s] = 0.f;
            int base = ttg * 8;
#pragma unroll
            for (int u = 0; u < 38; ++u) {
                float av = aw_s[base + u];
                float cv = awc_s[base + u];
#pragma unroll
                for (int s = 0; s < 8; ++s) {
                    int k = u - s;
                    if (k >= 0 && k < 31) {
                        acc[s] = fmaf(ka[k], av, acc[s]);
                        acc[s] = fmaf(kb_[k], cv, acc[s]);
                    }
                }
            }
#pragma unroll
            for (int s = 0; s < 8; ++s)
                locb[base + s][f] = __float2bfloat16(acc[s]);
        }
        __syncthreads();

        // phase C: energies via MFMA; wave w covers m-tiles 2w, 2w+1
        {
            int lane = tid & 63;
            int w    = tid >> 6;
            int c    = lane & 15, q = lane >> 4;

            bf16x8 Bf[8];
#pragma unroll
            for (int tc = 0; tc < 8; ++tc) {
                int d = tc * 16 + c;
                const float* lp = ldense + d * 32 + q * 8;
                float4 f0 = *(const float4*)lp;
                float4 f1 = *(const float4*)(lp + 4);
                union { bf16x8 vv; __hip_bfloat16 h[8]; } u;
                u.h[0] = __float2bfloat16(f0.x); u.h[1] = __float2bfloat16(f0.y);
                u.h[2] = __float2bfloat16(f0.z); u.h[3] = __float2bfloat16(f0.w);
                u.h[4] = __float2bfloat16(f1.x); u.h[5] = __float2bfloat16(f1.y);
                u.h[6] = __float2bfloat16(f1.z); u.h[7] = __float2bfloat16(f1.w);
                Bf[tc] = u.vv;
            }
#pragma unroll
            for (int half = 0; half < 2; ++half) {
                int mt = w * 2 + half;
                bf16x8 Af = *(const bf16x8*)&locb[mt * 16 + c][q * 8];
                f32x4 zero = {0.f, 0.f, 0.f, 0.f};
                float se[4] = {0.f, 0.f, 0.f, 0.f};
#pragma unroll
                for (int tc = 0; tc < 8; ++tc) {
                    f32x4 P = __builtin_amdgcn_mfma_f32_16x16x32_bf16(Af, Bf[tc], zero, 0, 0, 0);
                    int d = tc * 16 + c;
                    float vv = v[d];
                    float pqv = pq_s[d];
#pragma unroll
                    for (int r = 0; r < 4; ++r) {
                        int ttp = mt * 16 + q * 4 + r;
                        float x = P[r] + pqv + pm[((size_t)b << 15) + ttp * 128 + d];
                        se[r] = fmaf(ftanh(x), vv, se[r]);
                    }
                }
#pragma unroll
                for (int m = 1; m < 16; m <<= 1) {
#pragma unroll
                    for (int r = 0; r < 4; ++r) se[r] += __shfl_xor(se[r], m);
                }
                if (c == 0) {
#pragma unroll
                    for (int r = 0; r < 4; ++r) esh[mt * 16 + q * 4 + r] = se[r];
                }
            }
        }
        __syncthreads();

        // phase D: single-wave softmax
        if (tid < 64) {
            float ev[4];
            float mx = -1e30f;
#pragma unroll
            for (int r = 0; r < 4; ++r) {
                int tt = tid * 4 + r;
                ev[r] = (tt < len) ? esh[tt] : -1e9f;
                mx = fmaxf(mx, ev[r]);
            }
#pragma unroll
            for (int mm = 32; mm >= 1; mm >>= 1) mx = fmaxf(mx, __shfl_xor(mx, mm));
            float sum = 0.f;
#pragma unroll
            for (int r = 0; r < 4; ++r) {
                ev[r] = exp2f((ev[r] - mx) * 1.4426950408889634f);
                sum += ev[r];
            }
#pragma unroll
            for (int mm = 32; mm >= 1; mm >>= 1) sum += __shfl_xor(sum, mm);
            float winv = __builtin_amdgcn_rcpf(sum);
#pragma unroll
            for (int r = 0; r < 4; ++r) {
                int tt = tid * 4 + r;
                float wg = ev[r] * winv;
                wgt_s[tt] = wg;
                align_out[(size_t)b * 131072 + (size_t)t * 256 + tt] = wg;
                awc[b * 256 + tt] = awc_s[tt + 15] + wg;
            }
        }
        __syncthreads();

        // phase E: context (thread e, 4-way ILP over tt)
        {
            int e = tid;
            const float* mr = memory + (size_t)b * 131072 + e;
            float s0 = 0.f, s1 = 0.f, s2 = 0.f, s3 = 0.f;
            for (int tt = 0; tt < 256; tt += 4) {
                s0 = fmaf(wgt_s[tt],     mr[(size_t)tt * 512],       s0);
                s1 = fmaf(wgt_s[tt + 1], mr[(size_t)(tt + 1) * 512], s1);
                s2 = fmaf(wgt_s[tt + 2], mr[(size_t)(tt + 2) * 512], s2);
                s3 = fmaf(wgt_s[tt + 3], mr[(size_t)(tt + 3) * 512], s3);
            }
            float cv = (s0 + s1) + (s2 + s3);
            ctxf_cur[b * 512 + e] = cv;
            ctxb[b * 512 + e] = __float2bfloat16(cv);
        }
        __syncthreads();
        if (tid == 0) release_flag(doneC + b, t + 1);
        return;
    }

    if (blk < 544) {
        // ---------------- decoder-LSTM GEMM ----------------
        lstm_tile<2560, 1024, 512, 1024, 512, 1024, true, true>(
            smem, blk - 288, t + 1,
            ah_cur, ctxb, dh_prev,
            wswD, d_b, dc, dhf_cur, dh_cur, doneA, doneC, nullptr);
        return;
    }

    // ---------------- projection for step t-1 ----------------
    {
        if (t == 0) return;
        int b = blk - 544;
        int tp = t - 1;
        const float* dh = (tp & 1) ? dhf1 : dhf0;
        const float* cx = (tp & 1) ? ctxf1 : ctxf0;
        float* pi = (float*)smem;
        for (int i = tid; i < 1024; i += 512) pi[i] = dh[b * 1024 + i];
        if (tid < 512) pi[1024 + tid] = cx[b * 512 + tid];
        __syncthreads();
        int w = tid >> 6, lane = tid & 63;
        for (int o = w; o < 81; o += 8) {
            bool isGate = (o == 80);
            const float* wr = isGate ? gate_w : (proj_w + (size_t)o * 1536);
            float s = 0.f;
#pragma unroll
            for (int c = 0; c < 6; ++c) {
                float4 wv = *(const float4*)(wr + c * 256 + lane * 4);
                const float* pp = pi + c * 256 + lane * 4;
                s += wv.x * pp[0] + wv.y * pp[1] + wv.z * pp[2] + wv.w * pp[3];
            }
#pragma unroll
            for (int mm = 32; mm >= 1; mm >>= 1) s += __shfl_xor(s, mm);
            if (lane == 0) {
                if (isGate) out_gate[b * 512 + tp] = s + gate_b[0];
                else out_mel[(size_t)b * (80 * 512) + (size_t)o * 512 + tp]
                        = s + proj_b[o];
            }
        }
    }
}

// ============================================================
// Projection + gate (f32) — final timestep only
// ============================================================
__global__ __launch_bounds__(256) void proj_kernel(
    const float* __restrict__ dh,
    const float* __restrict__ ctx,
    const float* __restrict__ proj_w,
    const float* __restrict__ proj_b,
    const float* __restrict__ gate_w,
    const float* __restrict__ gate_b,
    float* __restrict__ out_mel,
    float* __restrict__ out_gate,
    int t)
{
    int b = blockIdx.x, tid = threadIdx.x;
    __shared__ float pi[1536];
    __shared__ float red[256];
    for (int i = tid; i < 1024; i += 256) pi[i] = dh[b * 1024 + i];
    for (int i = tid; i < 512; i += 256) pi[1024 + i] = ctx[b * 512 + i];
    __syncthreads();

    float s = 0.f;
    if (tid < 240) {
        int m = tid / 3, p = tid - m * 3;
        const float* wr = proj_w + (size_t)m * 1536 + p * 512;
        const float* pr = pi + p * 512;
        for (int k = 0; k < 512; ++k) s += wr[k] * pr[k];
    } else {
        int p = tid - 240;
        const float* wr = gate_w + p * 96;
        const float* pr = pi + p * 96;
        for (int k = 0; k < 96; ++k) s += wr[k] * pr[k];
    }
    red[tid] = s;
    __syncthreads();
    if (tid < 80) {
        float m3 = red[tid * 3] + red[tid * 3 + 1] + red[tid * 3 + 2];
        out_mel[(size_t)b * (80 * 512) + (size_t)tid * 512 + t] = m3 + proj_b[tid];
    } else if (tid == 80) {
        float g = gate_b[0];
#pragma unroll
        for (int p = 0; p < 16; ++p) g += red[240 + p];
        out_gate[b * 512 + t] = g;
    }
}

// ============================================================
extern "C" void kernel_launch(void* const* d_in, const int* in_sizes, int n_in,
                              void* d_out, int out_size, void* d_ws, size_t ws_size,
                              hipStream_t stream)
{
    const float* memory   = (const float*)d_in[0];
    const float* dec_in   = (const float*)d_in[1];
    const int*   mlen     = (const int*)  d_in[2];
    const float* pw1      = (const float*)d_in[3];
    const float* pw2      = (const float*)d_in[4];
    const float* a_wih    = (const float*)d_in[5];
    const float* a_whh    = (const float*)d_in[6];
    const float* a_b      = (const float*)d_in[7];
    const float* wq       = (const float*)d_in[8];
    const float* wm       = (const float*)d_in[9];
    const float* v        = (const float*)d_in[10];
    const float* lconv    = (const float*)d_in[11];
    const float* ldense   = (const float*)d_in[12];
    const float* d_wih    = (const float*)d_in[13];
    const float* d_whh    = (const float*)d_in[14];
    const float* d_b      = (const float*)d_in[15];
    const float* proj_w   = (const float*)d_in[16];
    const float* proj_b   = (const float*)d_in[17];
    const float* gate_w   = (const float*)d_in[18];
    const float* gate_b   = (const float*)d_in[19];

    char* ws = (char*)d_ws;
    __hip_bfloat16* x2b  = (__hip_bfloat16*)(ws + B_X2);
    float*          pm   = (float*)(ws + B_PM);
    __hip_bfloat16* wswA = (__hip_bfloat16*)(ws + B_WSA);
    __hip_bfloat16* wswD = (__hip_bfloat16*)(ws + B_WSD);
    __hip_bfloat16* ahb0 = (__hip_bfloat16*)(ws + B_AHB0);
    __hip_bfloat16* ahb1 = (__hip_bfloat16*)(ws + B_AHB1);
    __hip_bfloat16* dhb0 = (__hip_bfloat16*)(ws + B_DHB0);
    __hip_bfloat16* dhb1 = (__hip_bfloat16*)(ws + B_DHB1);
    __hip_bfloat16* ctxb = (__hip_bfloat16*)(ws + B_CTXB);
    float*          ac   = (float*)(ws + B_AC);
    float*          dc   = (float*)(ws + B_DC);
    float*          awcp = (float*)(ws + B_AWC);
    float*          ahf  = (float*)(ws + B_AHF);
    float*          dhf0 = (float*)(ws + B_DHF0);
    float*          dhf1 = (float*)(ws + B_DHF1);
    float*          ctxf0= (float*)(ws + B_CTXF0);
    float*          ctxf1= (float*)(ws + B_CTXF1);
    int*            doneA= (int*)(ws + B_DONE);
    int*            doneC= (int*)(ws + B_DONE + 1024);

    float* out       = (float*)d_out;
    float* out_mel   = out + OUT_MEL;
    float* out_gate  = out + OUT_GATE;
    float* out_align = out + OUT_ALIGN;

    hipMemsetAsync(ws + B_ZERO_START, 0, B_ZERO_BYTES, stream);
    hipMemsetAsync(ws + B_DONE, 0, 1152, stream);

    prenet_kernel<<<1024, 256, 0, stream>>>(dec_in, pw1, pw2, x2b);
    pm_kernel<<<dim3(16, 32), 128, 0, stream>>>(memory, wm, pm);
    swizzle_kernel<<<3584, 256, 0, stream>>>(a_wih, 768,  a_whh, 1024, wswA, 1792);
    swizzle_kernel<<<5120, 256, 0, stream>>>(d_wih, 1536, d_whh, 1024, wswD, 2560);

    for (int t = 0; t < 512; ++t) {
        step_kernel<<<576, 512, 0, stream>>>(
            memory, mlen, wq, v, lconv, ldense, pm,
            x2b, wswA, wswD, a_b, d_b, ac, dc, ahf,
            ahb0, ahb1, dhb0, dhb1, ctxb,
            ctxf0, ctxf1, dhf0, dhf1,
            awcp, out_align, out_mel, out_gate,
            proj_w, proj_b, gate_w, gate_b,
            doneA, doneC, t);
    }

    // final projection for t=511 (t odd -> dhf1/ctxf1)
    proj_kernel<<<32, 256, 0, stream>>>(
        dhf1, ctxf1, proj_w, proj_b, gate_w, gate_b,
        out_mel, out_gate, 511);
}

// Round 3
// 38716.742 us; speedup vs baseline: 1.4821x; 1.4821x over previous
//
#include <hip/hip_runtime.h>
#include <hip/hip_bf16.h>
#include <math.h>

typedef __attribute__((ext_vector_type(8))) short bf16x8;
typedef __attribute__((ext_vector_type(4))) float f32x4;

// ---- workspace byte offsets ----
#define B_X2    0u            // 512*32*256 bf16  = 8388608
#define B_PM    8388608u      // 32*256*128 f32   = 4194304
#define B_WSA   12582912u     // 4096*1792 bf16   = 14680064
#define B_WSD   27262976u     // 4096*2560 bf16   = 20971520
#define B_AHB0  48234496u     // 32*1024 bf16
#define B_AHB1  48300032u
#define B_DHB0  48365568u
#define B_DHB1  48431104u
#define B_CTXB  48496640u     // 32*512 bf16
#define B_AC    48529408u     // 32*1024 f32
#define B_DC    48660480u
#define B_AWC   48791552u     // 32*256 f32
#define B_ZERO_START 48234496u
#define B_ZERO_BYTES 589824u
#define B_AHF   48824320u     // 32*1024 f32
#define B_DHF0  48955392u     // 32*1024 f32
#define B_CTXF0 49086464u     // 32*512 f32
#define B_CTXF1 49152000u     // 32*512 f32
#define B_DHF1  49217536u     // 32*1024 f32
#define B_DONE  49348608u     // doneC 32 ints

// ---- output offsets (floats) ----
#define OUT_MEL   0u
#define OUT_GATE  1310720u
#define OUT_ALIGN 1327104u

// ---- shared memory overlay for fused attn+lstmD kernel ----
#define SM_BYTES 27392
// attn: locb @0 (20480), aw_s @20480, awc_s @21632, pq_s @22784,
//       red @23296 (2048), esh @25344, wgt_s @26368
// gemm: red @0 (16384), gsum @16384 (2176)

__device__ __forceinline__ float sigf(float x) { return 1.f / (1.f + expf(-x)); }
__device__ __forceinline__ float ftanh(float x) {
    float t = exp2f(x * 2.885390081777927f);
    return 1.f - 2.f * __builtin_amdgcn_rcpf(t + 1.f);
}

// ---- one-way flag protocol (agent scope, generation counters) ----
__device__ __forceinline__ void wait_flags32(const int* f, int target) {
    int lane = threadIdx.x & 63;
    for (;;) {
        bool ok = true;
        if (lane < 32)
            ok = (__hip_atomic_load(f + lane, __ATOMIC_RELAXED,
                                    __HIP_MEMORY_SCOPE_AGENT) == target);
        if (__all(ok)) break;
        __builtin_amdgcn_s_sleep(8);
    }
    __builtin_amdgcn_fence(__ATOMIC_ACQUIRE, "agent");
}
__device__ __forceinline__ void release_flag(int* slot, int target) {
    __builtin_amdgcn_fence(__ATOMIC_RELEASE, "agent");
    __hip_atomic_store(slot, target, __ATOMIC_RELAXED, __HIP_MEMORY_SCOPE_AGENT);
}

// ============================================================
// Prenet for all timesteps -> bf16 x2[t][b][256]
// ============================================================
__global__ __launch_bounds__(256) void prenet_kernel(
    const float* __restrict__ dec_in,
    const float* __restrict__ w1,
    const float* __restrict__ w2,
    __hip_bfloat16* __restrict__ x2)
{
    int b  = blockIdx.x & 31;
    int t0 = (blockIdx.x >> 5) * 16;
    __shared__ float xin[16][80];
    __shared__ float h1[16][257];

    for (int i = threadIdx.x; i < 16 * 80; i += 256) {
        int tt = i / 80, m = i - tt * 80;
        int t = t0 + tt;
        xin[tt][m] = (t == 0) ? 0.f
                   : dec_in[(size_t)b * 80 * 512 + (size_t)m * 512 + (t - 1)];
    }
    __syncthreads();
    for (int i = threadIdx.x; i < 16 * 256; i += 256) {
        int tt = i >> 8, p = i & 255;
        const float* wr = w1 + p * 80;
        float s = 0.f;
        for (int m = 0; m < 80; ++m) s += xin[tt][m] * wr[m];
        h1[tt][p] = fmaxf(s, 0.f);
    }
    __syncthreads();
    for (int i = threadIdx.x; i < 16 * 256; i += 256) {
        int tt = i >> 8, q = i & 255;
        const float* wr = w2 + q * 256;
        float s = 0.f;
        for (int p = 0; p < 256; ++p) s += h1[tt][p] * wr[p];
        int t = t0 + tt;
        x2[(size_t)t * (32 * 256) + b * 256 + q] = __float2bfloat16(fmaxf(s, 0.f));
    }
}

// ============================================================
// processed_memory (f32)
// ============================================================
__global__ __launch_bounds__(128) void pm_kernel(
    const float* __restrict__ memory,
    const float* __restrict__ wm,
    float* __restrict__ pm)
{
    int b = blockIdx.y, tt0 = blockIdx.x * 16;
    __shared__ float ms[16][513];
    for (int i = threadIdx.x; i < 16 * 512; i += 128) {
        int tt = i >> 9, e = i & 511;
        ms[tt][e] = memory[(size_t)b * 131072 + (size_t)(tt0 + tt) * 512 + e];
    }
    __syncthreads();
    int d = threadIdx.x;
    float acc[16];
#pragma unroll
    for (int i = 0; i < 16; ++i) acc[i] = 0.f;
    const float* wr = wm + d * 512;
    for (int e = 0; e < 512; ++e) {
        float w = wr[e];
#pragma unroll
        for (int ttl = 0; ttl < 16; ++ttl) acc[ttl] += w * ms[ttl][e];
    }
    for (int ttl = 0; ttl < 16; ++ttl)
        pm[(size_t)b * 32768 + (size_t)(tt0 + ttl) * 128 + d] = acc[ttl];
}

// ============================================================
// Weight swizzle (unchanged)
// ============================================================
__global__ __launch_bounds__(256) void swizzle_kernel(
    const float* __restrict__ wih, int Kih,
    const float* __restrict__ whh, int Khh,
    __hip_bfloat16* __restrict__ out, int K)
{
    int idx = blockIdx.x * 256 + threadIdx.x;
    int lane = idx & 63;
    int tk = idx >> 6;
    int KB = K >> 5;
    int nt = tk / KB, kb = tk - nt * KB;
    int c = lane & 15;
    int n = (c >> 2) * 1024 + nt * 4 + (c & 3);
    int k = kb * 32 + ((lane >> 4) << 3);
    const float* src; int kk;
    if (k < Kih) { src = wih + (size_t)n * Kih; kk = k; }
    else         { src = whh + (size_t)n * Khh; kk = k - Kih; }
    __hip_bfloat16* op = out + (size_t)idx * 8;
#pragma unroll
    for (int j = 0; j < 8; ++j) op[j] = __float2bfloat16(src[kk + j]);
}

// ============================================================
// Kernel A: lstmA GEMM tiles (blocks 0..255) + proj(t-1) (256..319)
// — identical structure to the proven round-1 kernel.
// ============================================================
__global__ __launch_bounds__(512, 2) void lstmA_proj_kernel(
    const __hip_bfloat16* __restrict__ seg0,   // x2[t]
    const __hip_bfloat16* __restrict__ seg1,   // ctxb
    const __hip_bfloat16* __restrict__ seg2,   // ah_prev
    const __hip_bfloat16* __restrict__ wsw,
    const float* __restrict__ bias,
    float* __restrict__ c_state,
    float* __restrict__ h_f32,
    __hip_bfloat16* __restrict__ h_bf16,
    const float* __restrict__ proj_w,
    const float* __restrict__ proj_b,
    const float* __restrict__ gate_w,
    const float* __restrict__ gate_b,
    const float* __restrict__ dh_in,
    const float* __restrict__ ctx_in,
    float* __restrict__ out_mel,
    float* __restrict__ out_gate,
    int tprev)
{
    constexpr int K = 1792, S0 = 256, S1 = 512;
    constexpr int S0STR = 256, S1STR = 512, S2STR = 1024;
    constexpr int KB  = K / 32;
    constexpr int NCH = K / 256;

    __shared__ float red[8][2][4][64];
    __shared__ float gsum[32][17];
    __shared__ float pi[1536];

    if (blockIdx.x >= 256) {
        // ---------- projection path: 64 blocks, 2 per batch ----------
        if (tprev < 0) return;
        int pb = blockIdx.x - 256;
        int b = pb >> 1, half = pb & 1;
        for (int i = threadIdx.x; i < 1024; i += 512) pi[i] = dh_in[b * 1024 + i];
        if (threadIdx.x < 512) pi[1024 + threadIdx.x] = ctx_in[b * 512 + threadIdx.x];
        __syncthreads();
        int w = threadIdx.x >> 6, lane = threadIdx.x & 63;
        int nOut = half ? 41 : 40;
        for (int o = w; o < nOut; o += 8) {
            bool isGate = (half && o == 40);
            int m = half * 40 + o;
            const float* wr = isGate ? gate_w : (proj_w + (size_t)m * 1536);
            float s = 0.f;
#pragma unroll
            for (int c = 0; c < 6; ++c) {
                float4 wv = *(const float4*)(wr + c * 256 + lane * 4);
                const float* pp = pi + c * 256 + lane * 4;
                s += wv.x * pp[0] + wv.y * pp[1] + wv.z * pp[2] + wv.w * pp[3];
            }
#pragma unroll
            for (int mm = 32; mm >= 1; mm >>= 1) s += __shfl_xor(s, mm);
            if (lane == 0) {
                if (isGate) out_gate[b * 512 + tprev] = s + gate_b[0];
                else out_mel[(size_t)b * (80 * 512) + (size_t)m * 512 + tprev]
                        = s + proj_b[m];
            }
        }
        return;
    }

    // ---------- GEMM path ----------
    int nt   = blockIdx.x;
    int tid  = threadIdx.x;
    int lane = tid & 63;
    int w    = tid >> 6;
    int r0   = lane & 15;
    int kq   = (lane >> 4) << 3;

    const __hip_bfloat16* wp = wsw + (((size_t)nt * KB + (size_t)w * NCH) * 64 + lane) * 8;
    f32x4 acc0 = {0.f, 0.f, 0.f, 0.f};
    f32x4 acc1 = {0.f, 0.f, 0.f, 0.f};
    int k0 = w * (K / 8);

#pragma unroll
    for (int i = 0; i < NCH; ++i) {
        int kc = k0 + i * 32;
        const __hip_bfloat16* sp; int sstr, off;
        if (kc < S0)           { sp = seg0; sstr = S0STR; off = kc; }
        else if (kc < S0 + S1) { sp = seg1; sstr = S1STR; off = kc - S0; }
        else                   { sp = seg2; sstr = S2STR; off = kc - S0 - S1; }
        int ko = off + kq;
        bf16x8 a0 = *(const bf16x8*)(sp + (size_t)r0 * sstr + ko);
        bf16x8 a1 = *(const bf16x8*)(sp + (size_t)(r0 + 16) * sstr + ko);
        bf16x8 bb = *(const bf16x8*)(wp + (size_t)i * 512);
        acc0 = __builtin_amdgcn_mfma_f32_16x16x32_bf16(a0, bb, acc0, 0, 0, 0);
        acc1 = __builtin_amdgcn_mfma_f32_16x16x32_bf16(a1, bb, acc1, 0, 0, 0);
    }

#pragma unroll
    for (int r = 0; r < 4; ++r) {
        red[w][0][r][lane] = acc0[r];
        red[w][1][r][lane] = acc1[r];
    }
    __syncthreads();

    {
        int b = tid >> 4, c = tid & 15;
        int mt = b >> 4, bm = b & 15;
        int lidx = ((bm >> 2) << 4) + c, rg = bm & 3;
        float s = 0.f;
#pragma unroll
        for (int ks = 0; ks < 8; ++ks) s += red[ks][mt][rg][lidx];
        gsum[b][c] = s;
    }
    __syncthreads();

    if (tid < 128) {
        int b = tid & 31, jl = tid >> 5;
        int j = nt * 4 + jl;
        float gi = gsum[b][jl]      + bias[j];
        float gf = gsum[b][4 + jl]  + bias[1024 + j];
        float gg = gsum[b][8 + jl]  + bias[2048 + j];
        float go = gsum[b][12 + jl] + bias[3072 + j];
        float cv = c_state[b * 1024 + j];
        float c2 = sigf(gf) * cv + sigf(gi) * tanhf(gg);
        float h2 = sigf(go) * tanhf(c2);
        c_state[b * 1024 + j] = c2;
        h_f32[b * 1024 + j]   = h2;
        h_bf16[b * 1024 + j]  = __float2bfloat16(h2);
    }
}

// ============================================================
// Kernel B: attention (blocks 0..31, no waits) + lstmD tiles
// (blocks 32..287; only waves 3,4 spin on the 32-entry doneC).
// One-way dep, 288 blocks all co-resident -> deadlock-free.
// ============================================================
__global__ __launch_bounds__(512, 2) void attn_lstmD_kernel(
    const float* __restrict__ memory,
    const int*   __restrict__ mlen,
    const float* __restrict__ wq,
    const float* __restrict__ v,
    const float* __restrict__ lconv,
    const float* __restrict__ ldense,
    const float* __restrict__ pm,
    const float* __restrict__ ahf,
    const __hip_bfloat16* __restrict__ ah_cur,   // seg0 for lstmD
    const __hip_bfloat16* __restrict__ dh_prev,  // seg2 for lstmD
    __hip_bfloat16* __restrict__ ctxb,           // seg1, written by attn
    const __hip_bfloat16* __restrict__ wswD,
    const float* __restrict__ d_b,
    float* __restrict__ dc,
    float* __restrict__ dhf_cur,
    __hip_bfloat16* __restrict__ dh_cur,
    float* __restrict__ ctxf_cur,
    float* __restrict__ awc,
    float* __restrict__ align_out,
    int* __restrict__ doneC,
    int t)
{
    __shared__ char smem[SM_BYTES];
    int blk = blockIdx.x;
    int tid = threadIdx.x;

    if (blk < 32) {
        // ---------------- attention (512 threads) ----------------
        int b = blk;
        __hip_bfloat16 (*locb)[40] = (__hip_bfloat16(*)[40])smem;
        float* aw_s  = (float*)(smem + 20480);
        float* awc_s = (float*)(smem + 21632);
        float* pq_s  = (float*)(smem + 22784);
        float* red   = (float*)(smem + 23296);
        float* esh   = (float*)(smem + 25344);
        float* wgt_s = (float*)(smem + 26368);

        int len = mlen[b];

        // phase A: stage aw/awc halo + pq partials
        if (tid < 288) {
            int tt = tid - 15;
            float a = 0.f, c = 0.f;
            if (tt >= 0 && tt < 256) {
                a = (t == 0) ? 0.f
                  : align_out[(size_t)b * 131072 + (size_t)(t - 1) * 256 + tt];
                c = awc[b * 256 + tt];
            }
            aw_s[tid] = a; awc_s[tid] = c;
        }
        {
            int d = tid >> 2, p = tid & 3;
            const float4* wr = (const float4*)(wq + (size_t)d * 1024 + p * 256);
            const float4* hr = (const float4*)(ahf + b * 1024 + p * 256);
            float s = 0.f;
#pragma unroll 8
            for (int k = 0; k < 64; ++k) {
                float4 a = wr[k], h4 = hr[k];
                s += a.x * h4.x + a.y * h4.y + a.z * h4.z + a.w * h4.w;
            }
            red[tid] = s;
        }
        __syncthreads();

        // phase B: pq reduce + location conv (2 items/thread)
        if (tid < 128)
            pq_s[tid] = red[tid * 4] + red[tid * 4 + 1]
                      + red[tid * 4 + 2] + red[tid * 4 + 3];
        for (int it = 0; it < 2; ++it) {
            int item = tid + it * 512;
            int f = item >> 5, ttg = item & 31;
            const float* kcA = lconv + f * 62;
            const float* kcB = kcA + 31;
            float ka[31], kb_[31];
#pragma unroll
            for (int k = 0; k < 31; ++k) { ka[k] = kcA[k]; kb_[k] = kcB[k]; }
            float acc[8];
#pragma unroll
            for (int s = 0; s < 8; ++s) acc[s] = 0.f;
            int base = ttg * 8;
#pragma unroll
            for (int u = 0; u < 38; ++u) {
                float av = aw_s[base + u];
                float cv = awc_s[base + u];
#pragma unroll
                for (int s = 0; s < 8; ++s) {
                    int k = u - s;
                    if (k >= 0 && k < 31) {
                        acc[s] = fmaf(ka[k], av, acc[s]);
                        acc[s] = fmaf(kb_[k], cv, acc[s]);
                    }
                }
            }
#pragma unroll
            for (int s = 0; s < 8; ++s)
                locb[base + s][f] = __float2bfloat16(acc[s]);
        }
        __syncthreads();

        // phase C: energies via MFMA; wave w covers m-tiles 2w, 2w+1
        {
            int lane = tid & 63;
            int w    = tid >> 6;
            int c    = lane & 15, q = lane >> 4;

            bf16x8 Bf[8];
#pragma unroll
            for (int tc = 0; tc < 8; ++tc) {
                int d = tc * 16 + c;
                const float* lp = ldense + d * 32 + q * 8;
                float4 f0 = *(const float4*)lp;
                float4 f1 = *(const float4*)(lp + 4);
                union { bf16x8 vv; __hip_bfloat16 h[8]; } u;
                u.h[0] = __float2bfloat16(f0.x); u.h[1] = __float2bfloat16(f0.y);
                u.h[2] = __float2bfloat16(f0.z); u.h[3] = __float2bfloat16(f0.w);
                u.h[4] = __float2bfloat16(f1.x); u.h[5] = __float2bfloat16(f1.y);
                u.h[6] = __float2bfloat16(f1.z); u.h[7] = __float2bfloat16(f1.w);
                Bf[tc] = u.vv;
            }
#pragma unroll
            for (int half = 0; half < 2; ++half) {
                int mt = w * 2 + half;
                bf16x8 Af = *(const bf16x8*)&locb[mt * 16 + c][q * 8];
                f32x4 zero = {0.f, 0.f, 0.f, 0.f};
                float se[4] = {0.f, 0.f, 0.f, 0.f};
#pragma unroll
                for (int tc = 0; tc < 8; ++tc) {
                    f32x4 P = __builtin_amdgcn_mfma_f32_16x16x32_bf16(Af, Bf[tc], zero, 0, 0, 0);
                    int d = tc * 16 + c;
                    float vv = v[d];
                    float pqv = pq_s[d];
#pragma unroll
                    for (int r = 0; r < 4; ++r) {
                        int ttp = mt * 16 + q * 4 + r;
                        float x = P[r] + pqv + pm[((size_t)b << 15) + ttp * 128 + d];
                        se[r] = fmaf(ftanh(x), vv, se[r]);
                    }
                }
#pragma unroll
                for (int m = 1; m < 16; m <<= 1) {
#pragma unroll
                    for (int r = 0; r < 4; ++r) se[r] += __shfl_xor(se[r], m);
                }
                if (c == 0) {
#pragma unroll
                    for (int r = 0; r < 4; ++r) esh[mt * 16 + q * 4 + r] = se[r];
                }
            }
        }
        __syncthreads();

        // phase D: single-wave softmax
        if (tid < 64) {
            float ev[4];
            float mx = -1e30f;
#pragma unroll
            for (int r = 0; r < 4; ++r) {
                int tt = tid * 4 + r;
                ev[r] = (tt < len) ? esh[tt] : -1e9f;
                mx = fmaxf(mx, ev[r]);
            }
#pragma unroll
            for (int mm = 32; mm >= 1; mm >>= 1) mx = fmaxf(mx, __shfl_xor(mx, mm));
            float sum = 0.f;
#pragma unroll
            for (int r = 0; r < 4; ++r) {
                ev[r] = exp2f((ev[r] - mx) * 1.4426950408889634f);
                sum += ev[r];
            }
#pragma unroll
            for (int mm = 32; mm >= 1; mm >>= 1) sum += __shfl_xor(sum, mm);
            float winv = __builtin_amdgcn_rcpf(sum);
#pragma unroll
            for (int r = 0; r < 4; ++r) {
                int tt = tid * 4 + r;
                float wg = ev[r] * winv;
                wgt_s[tt] = wg;
                align_out[(size_t)b * 131072 + (size_t)t * 256 + tt] = wg;
                awc[b * 256 + tt] = awc_s[tt + 15] + wg;
            }
        }
        __syncthreads();

        // phase E: context (thread e, 4-way ILP over tt)
        {
            int e = tid;
            const float* mr = memory + (size_t)b * 131072 + e;
            float s0 = 0.f, s1 = 0.f, s2 = 0.f, s3 = 0.f;
            for (int tt = 0; tt < 256; tt += 4) {
                s0 = fmaf(wgt_s[tt],     mr[(size_t)tt * 512],       s0);
                s1 = fmaf(wgt_s[tt + 1], mr[(size_t)(tt + 1) * 512], s1);
                s2 = fmaf(wgt_s[tt + 2], mr[(size_t)(tt + 2) * 512], s2);
                s3 = fmaf(wgt_s[tt + 3], mr[(size_t)(tt + 3) * 512], s3);
            }
            float cv = (s0 + s1) + (s2 + s3);
            ctxf_cur[b * 512 + e] = cv;
            ctxb[b * 512 + e] = __float2bfloat16(cv);
        }
        __syncthreads();
        if (tid == 0) release_flag(doneC + b, t + 1);
        return;
    }

    // ---------------- decoder-LSTM GEMM tile ----------------
    {
        constexpr int K = 2560, S0 = 1024, S1 = 512;
        constexpr int S0STR = 1024, S1STR = 512, S2STR = 1024;
        constexpr int KB  = K / 32;
        constexpr int NCH = K / 256;

        float (*red)[2][4][64] = (float(*)[2][4][64])smem;
        float (*gsum)[17]      = (float(*)[17])(smem + 16384);

        int nt   = blk - 32;
        int lane = tid & 63;
        int w    = tid >> 6;
        int r0   = lane & 15;
        int kq   = (lane >> 4) << 3;

        // only the ctx-range waves wait on attention
        if (w == 3 || w == 4) wait_flags32(doneC, t + 1);

        const __hip_bfloat16* wp = wswD + (((size_t)nt * KB + (size_t)w * NCH) * 64 + lane) * 8;
        f32x4 acc0 = {0.f, 0.f, 0.f, 0.f};
        f32x4 acc1 = {0.f, 0.f, 0.f, 0.f};
        int k0 = w * (K / 8);

#pragma unroll
        for (int i = 0; i < NCH; ++i) {
            int kc = k0 + i * 32;
            const __hip_bfloat16* sp; int sstr, off;
            if (kc < S0)           { sp = ah_cur;  sstr = S0STR; off = kc; }
            else if (kc < S0 + S1) { sp = ctxb;    sstr = S1STR; off = kc - S0; }
            else                   { sp = dh_prev; sstr = S2STR; off = kc - S0 - S1; }
            int ko = off + kq;
            bf16x8 a0 = *(const bf16x8*)(sp + (size_t)r0 * sstr + ko);
            bf16x8 a1 = *(const bf16x8*)(sp + (size_t)(r0 + 16) * sstr + ko);
            bf16x8 bb = *(const bf16x8*)(wp + (size_t)i * 512);
            acc0 = __builtin_amdgcn_mfma_f32_16x16x32_bf16(a0, bb, acc0, 0, 0, 0);
            acc1 = __builtin_amdgcn_mfma_f32_16x16x32_bf16(a1, bb, acc1, 0, 0, 0);
        }

#pragma unroll
        for (int r = 0; r < 4; ++r) {
            red[w][0][r][lane] = acc0[r];
            red[w][1][r][lane] = acc1[r];
        }
        __syncthreads();

        {
            int b = tid >> 4, c = tid & 15;
            int mt = b >> 4, bm = b & 15;
            int lidx = ((bm >> 2) << 4) + c, rg = bm & 3;
            float s = 0.f;
#pragma unroll
            for (int ks = 0; ks < 8; ++ks) s += red[ks][mt][rg][lidx];
            gsum[b][c] = s;
        }
        __syncthreads();

        if (tid < 128) {
            int b = tid & 31, jl = tid >> 5;
            int j = nt * 4 + jl;
            float gi = gsum[b][jl]      + d_b[j];
            float gf = gsum[b][4 + jl]  + d_b[1024 + j];
            float gg = gsum[b][8 + jl]  + d_b[2048 + j];
            float go = gsum[b][12 + jl] + d_b[3072 + j];
            float cv = dc[b * 1024 + j];
            float c2 = sigf(gf) * cv + sigf(gi) * tanhf(gg);
            float h2 = sigf(go) * tanhf(c2);
            dc[b * 1024 + j] = c2;
            dhf_cur[b * 1024 + j] = h2;
            dh_cur[b * 1024 + j]  = __float2bfloat16(h2);
        }
    }
}

// ============================================================
// Projection + gate (f32) — final timestep only
// ============================================================
__global__ __launch_bounds__(256) void proj_kernel(
    const float* __restrict__ dh,
    const float* __restrict__ ctx,
    const float* __restrict__ proj_w,
    const float* __restrict__ proj_b,
    const float* __restrict__ gate_w,
    const float* __restrict__ gate_b,
    float* __restrict__ out_mel,
    float* __restrict__ out_gate,
    int t)
{
    int b = blockIdx.x, tid = threadIdx.x;
    __shared__ float pi[1536];
    __shared__ float red[256];
    for (int i = tid; i < 1024; i += 256) pi[i] = dh[b * 1024 + i];
    for (int i = tid; i < 512; i += 256) pi[1024 + i] = ctx[b * 512 + i];
    __syncthreads();

    float s = 0.f;
    if (tid < 240) {
        int m = tid / 3, p = tid - m * 3;
        const float* wr = proj_w + (size_t)m * 1536 + p * 512;
        const float* pr = pi + p * 512;
        for (int k = 0; k < 512; ++k) s += wr[k] * pr[k];
    } else {
        int p = tid - 240;
        const float* wr = gate_w + p * 96;
        const float* pr = pi + p * 96;
        for (int k = 0; k < 96; ++k) s += wr[k] * pr[k];
    }
    red[tid] = s;
    __syncthreads();
    if (tid < 80) {
        float m3 = red[tid * 3] + red[tid * 3 + 1] + red[tid * 3 + 2];
        out_mel[(size_t)b * (80 * 512) + (size_t)tid * 512 + t] = m3 + proj_b[tid];
    } else if (tid == 80) {
        float g = gate_b[0];
#pragma unroll
        for (int p = 0; p < 16; ++p) g += red[240 + p];
        out_gate[b * 512 + t] = g;
    }
}

// ============================================================
extern "C" void kernel_launch(void* const* d_in, const int* in_sizes, int n_in,
                              void* d_out, int out_size, void* d_ws, size_t ws_size,
                              hipStream_t stream)
{
    const float* memory   = (const float*)d_in[0];
    const float* dec_in   = (const float*)d_in[1];
    const int*   mlen     = (const int*)  d_in[2];
    const float* pw1      = (const float*)d_in[3];
    const float* pw2      = (const float*)d_in[4];
    const float* a_wih    = (const float*)d_in[5];
    const float* a_whh    = (const float*)d_in[6];
    const float* a_b      = (const float*)d_in[7];
    const float* wq       = (const float*)d_in[8];
    const float* wm       = (const float*)d_in[9];
    const float* v        = (const float*)d_in[10];
    const float* lconv    = (const float*)d_in[11];
    const float* ldense   = (const float*)d_in[12];
    const float* d_wih    = (const float*)d_in[13];
    const float* d_whh    = (const float*)d_in[14];
    const float* d_b      = (const float*)d_in[15];
    const float* proj_w   = (const float*)d_in[16];
    const float* proj_b   = (const float*)d_in[17];
    const float* gate_w   = (const float*)d_in[18];
    const float* gate_b   = (const float*)d_in[19];

    char* ws = (char*)d_ws;
    __hip_bfloat16* x2b  = (__hip_bfloat16*)(ws + B_X2);
    float*          pm   = (float*)(ws + B_PM);
    __hip_bfloat16* wswA = (__hip_bfloat16*)(ws + B_WSA);
    __hip_bfloat16* wswD = (__hip_bfloat16*)(ws + B_WSD);
    __hip_bfloat16* ahb0 = (__hip_bfloat16*)(ws + B_AHB0);
    __hip_bfloat16* ahb1 = (__hip_bfloat16*)(ws + B_AHB1);
    __hip_bfloat16* dhb0 = (__hip_bfloat16*)(ws + B_DHB0);
    __hip_bfloat16* dhb1 = (__hip_bfloat16*)(ws + B_DHB1);
    __hip_bfloat16* ctxb = (__hip_bfloat16*)(ws + B_CTXB);
    float*          ac   = (float*)(ws + B_AC);
    float*          dc   = (float*)(ws + B_DC);
    float*          awcp = (float*)(ws + B_AWC);
    float*          ahf  = (float*)(ws + B_AHF);
    float*          dhf0 = (float*)(ws + B_DHF0);
    float*          dhf1 = (float*)(ws + B_DHF1);
    float*          ctxf0= (float*)(ws + B_CTXF0);
    float*          ctxf1= (float*)(ws + B_CTXF1);
    int*            doneC= (int*)(ws + B_DONE);

    float* out       = (float*)d_out;
    float* out_mel   = out + OUT_MEL;
    float* out_gate  = out + OUT_GATE;
    float* out_align = out + OUT_ALIGN;

    hipMemsetAsync(ws + B_ZERO_START, 0, B_ZERO_BYTES, stream);
    hipMemsetAsync(ws + B_DONE, 0, 128, stream);

    prenet_kernel<<<1024, 256, 0, stream>>>(dec_in, pw1, pw2, x2b);
    pm_kernel<<<dim3(16, 32), 128, 0, stream>>>(memory, wm, pm);
    swizzle_kernel<<<3584, 256, 0, stream>>>(a_wih, 768,  a_whh, 1024, wswA, 1792);
    swizzle_kernel<<<5120, 256, 0, stream>>>(d_wih, 1536, d_whh, 1024, wswD, 2560);

    for (int t = 0; t < 512; ++t) {
        __hip_bfloat16* ah_prev = (t & 1) ? ahb1 : ahb0;
        __hip_bfloat16* ah_cur  = (t & 1) ? ahb0 : ahb1;
        __hip_bfloat16* dh_prev = (t & 1) ? dhb1 : dhb0;
        __hip_bfloat16* dh_cur  = (t & 1) ? dhb0 : dhb1;
        float* ctxf_cur = (t & 1) ? ctxf1 : ctxf0;
        float* dhf_cur  = (t & 1) ? dhf1  : dhf0;
        const float* dhf_prev  = (t & 1) ? dhf0  : dhf1;
        const float* ctxf_prev = (t & 1) ? ctxf0 : ctxf1;

        lstmA_proj_kernel<<<320, 512, 0, stream>>>(
            x2b + (size_t)t * 8192, ctxb, ah_prev,
            wswA, a_b, ac, ahf, ah_cur,
            proj_w, proj_b, gate_w, gate_b,
            dhf_prev, ctxf_prev, out_mel, out_gate, t - 1);

        attn_lstmD_kernel<<<288, 512, 0, stream>>>(
            memory, mlen, wq, v, lconv, ldense, pm, ahf,
            ah_cur, dh_prev, ctxb, wswD, d_b, dc,
            dhf_cur, dh_cur, ctxf_cur,
            awcp, out_align, doneC, t);
    }

    // final projection for t=511 (t odd -> dhf1/ctxf1)
    proj_kernel<<<32, 256, 0, stream>>>(
        dhf1, ctxf1, proj_w, proj_b, gate_w, gate_b,
        out_mel, out_gate, 511);
}

// Round 4
// 34539.511 us; speedup vs baseline: 1.6613x; 1.1209x over previous
//
#include <hip/hip_runtime.h>
#include <hip/hip_bf16.h>
#include <math.h>

typedef __attribute__((ext_vector_type(8))) short bf16x8;
typedef __attribute__((ext_vector_type(4))) float f32x4;

// ---- workspace byte offsets ----
#define B_X2    0u            // 512*32*256 bf16  = 8388608
#define B_PM    8388608u      // 32*256*128 f32   = 4194304
#define B_WSA   12582912u     // 4096*1792 bf16   = 14680064
#define B_WSD   27262976u     // 4096*2560 bf16   = 20971520
#define B_AHB0  48234496u     // 32*1024 bf16
#define B_AHB1  48300032u
#define B_DHB0  48365568u
#define B_DHB1  48431104u
#define B_CTXB  48496640u     // 32*512 bf16
#define B_AC    48529408u     // 32*1024 f32
#define B_DC    48660480u
#define B_AWC   48791552u     // 32*256 f32
#define B_ZERO_START 48234496u
#define B_ZERO_BYTES 589824u
#define B_AHF   48824320u     // 32*1024 f32
#define B_DHF0  48955392u     // 32*1024 f32
#define B_CTXF0 49086464u     // 32*512 f32
#define B_CTXF1 49152000u     // 32*512 f32
#define B_DHF1  49217536u     // 32*1024 f32
#define B_LPM   49348608u     // 32*256*128 f32 = 4194304  (loc+pm precompute)

// ---- output offsets (floats) ----
#define OUT_MEL   0u
#define OUT_GATE  1310720u
#define OUT_ALIGN 1327104u

// ---- shared memory for Q kernel (max of role needs) ----
#define QSM_BYTES 23040
// lstm: red @0 (16384), gsum @16384 (2176)            = 18560
// lpm : locb @0 (20480), aw_s @20480, awc_s @21632    = 22784
// proj: pi @0 (6144)

__device__ __forceinline__ float sigf(float x) { return 1.f / (1.f + expf(-x)); }
__device__ __forceinline__ float ftanh(float x) {
    float t = exp2f(x * 2.885390081777927f);
    return 1.f - 2.f * __builtin_amdgcn_rcpf(t + 1.f);
}

// buffer-parity helpers: buffer holding state of step s
#define HOLD(s, b0, b1) (((s) & 1) ? (b0) : (b1))

// ============================================================
// Prenet for all timesteps -> bf16 x2[t][b][256]
// ============================================================
__global__ __launch_bounds__(256) void prenet_kernel(
    const float* __restrict__ dec_in,
    const float* __restrict__ w1,
    const float* __restrict__ w2,
    __hip_bfloat16* __restrict__ x2)
{
    int b  = blockIdx.x & 31;
    int t0 = (blockIdx.x >> 5) * 16;
    __shared__ float xin[16][80];
    __shared__ float h1[16][257];

    for (int i = threadIdx.x; i < 16 * 80; i += 256) {
        int tt = i / 80, m = i - tt * 80;
        int t = t0 + tt;
        xin[tt][m] = (t == 0) ? 0.f
                   : dec_in[(size_t)b * 80 * 512 + (size_t)m * 512 + (t - 1)];
    }
    __syncthreads();
    for (int i = threadIdx.x; i < 16 * 256; i += 256) {
        int tt = i >> 8, p = i & 255;
        const float* wr = w1 + p * 80;
        float s = 0.f;
        for (int m = 0; m < 80; ++m) s += xin[tt][m] * wr[m];
        h1[tt][p] = fmaxf(s, 0.f);
    }
    __syncthreads();
    for (int i = threadIdx.x; i < 16 * 256; i += 256) {
        int tt = i >> 8, q = i & 255;
        const float* wr = w2 + q * 256;
        float s = 0.f;
        for (int p = 0; p < 256; ++p) s += h1[tt][p] * wr[p];
        int t = t0 + tt;
        x2[(size_t)t * (32 * 256) + b * 256 + q] = __float2bfloat16(fmaxf(s, 0.f));
    }
}

// ============================================================
// processed_memory (f32)
// ============================================================
__global__ __launch_bounds__(128) void pm_kernel(
    const float* __restrict__ memory,
    const float* __restrict__ wm,
    float* __restrict__ pm)
{
    int b = blockIdx.y, tt0 = blockIdx.x * 16;
    __shared__ float ms[16][513];
    for (int i = threadIdx.x; i < 16 * 512; i += 128) {
        int tt = i >> 9, e = i & 511;
        ms[tt][e] = memory[(size_t)b * 131072 + (size_t)(tt0 + tt) * 512 + e];
    }
    __syncthreads();
    int d = threadIdx.x;
    float acc[16];
#pragma unroll
    for (int i = 0; i < 16; ++i) acc[i] = 0.f;
    const float* wr = wm + d * 512;
    for (int e = 0; e < 512; ++e) {
        float w = wr[e];
#pragma unroll
        for (int ttl = 0; ttl < 16; ++ttl) acc[ttl] += w * ms[ttl][e];
    }
    for (int ttl = 0; ttl < 16; ++ttl)
        pm[(size_t)b * 32768 + (size_t)(tt0 + ttl) * 128 + d] = acc[ttl];
}

// ============================================================
// Weight swizzle (unchanged)
// ============================================================
__global__ __launch_bounds__(256) void swizzle_kernel(
    const float* __restrict__ wih, int Kih,
    const float* __restrict__ whh, int Khh,
    __hip_bfloat16* __restrict__ out, int K)
{
    int idx = blockIdx.x * 256 + threadIdx.x;
    int lane = idx & 63;
    int tk = idx >> 6;
    int KB = K >> 5;
    int nt = tk / KB, kb = tk - nt * KB;
    int c = lane & 15;
    int n = (c >> 2) * 1024 + nt * 4 + (c & 3);
    int k = kb * 32 + ((lane >> 4) << 3);
    const float* src; int kk;
    if (k < Kih) { src = wih + (size_t)n * Kih; kk = k; }
    else         { src = whh + (size_t)n * Khh; kk = k - Kih; }
    __hip_bfloat16* op = out + (size_t)idx * 8;
#pragma unroll
    for (int j = 0; j < 8; ++j) op[j] = __float2bfloat16(src[kk + j]);
}

// ============================================================
// LSTM gates GEMM tile + epilogue (device fn, 512 threads, no sync flags)
// ============================================================
template<int K, int S0, int S1, int S0STR, int S1STR, int S2STR>
__device__ __forceinline__ void lstm_tile(
    char* smem, int nt,
    const __hip_bfloat16* __restrict__ seg0,
    const __hip_bfloat16* __restrict__ seg1,
    const __hip_bfloat16* __restrict__ seg2,
    const __hip_bfloat16* __restrict__ wsw,
    const float* __restrict__ bias,
    float* __restrict__ c_state,
    float* __restrict__ h_f32,
    __hip_bfloat16* __restrict__ h_bf16)
{
    constexpr int KB  = K / 32;
    constexpr int NCH = K / 256;

    float (*red)[2][4][64] = (float(*)[2][4][64])smem;
    float (*gsum)[17]      = (float(*)[17])(smem + 16384);

    int tid  = threadIdx.x;
    int lane = tid & 63;
    int w    = tid >> 6;
    int r0   = lane & 15;
    int kq   = (lane >> 4) << 3;

    const __hip_bfloat16* wp = wsw + (((size_t)nt * KB + (size_t)w * NCH) * 64 + lane) * 8;
    f32x4 acc0 = {0.f, 0.f, 0.f, 0.f};
    f32x4 acc1 = {0.f, 0.f, 0.f, 0.f};
    int k0 = w * (K / 8);

#pragma unroll
    for (int i = 0; i < NCH; ++i) {
        int kc = k0 + i * 32;
        const __hip_bfloat16* sp; int sstr, off;
        if (kc < S0)           { sp = seg0; sstr = S0STR; off = kc; }
        else if (kc < S0 + S1) { sp = seg1; sstr = S1STR; off = kc - S0; }
        else                   { sp = seg2; sstr = S2STR; off = kc - S0 - S1; }
        int ko = off + kq;
        bf16x8 a0 = *(const bf16x8*)(sp + (size_t)r0 * sstr + ko);
        bf16x8 a1 = *(const bf16x8*)(sp + (size_t)(r0 + 16) * sstr + ko);
        bf16x8 bb = *(const bf16x8*)(wp + (size_t)i * 512);
        acc0 = __builtin_amdgcn_mfma_f32_16x16x32_bf16(a0, bb, acc0, 0, 0, 0);
        acc1 = __builtin_amdgcn_mfma_f32_16x16x32_bf16(a1, bb, acc1, 0, 0, 0);
    }

#pragma unroll
    for (int r = 0; r < 4; ++r) {
        red[w][0][r][lane] = acc0[r];
        red[w][1][r][lane] = acc1[r];
    }
    __syncthreads();

    {
        int b = tid >> 4, c = tid & 15;
        int mt = b >> 4, bm = b & 15;
        int lidx = ((bm >> 2) << 4) + c, rg = bm & 3;
        float s = 0.f;
#pragma unroll
        for (int ks = 0; ks < 8; ++ks) s += red[ks][mt][rg][lidx];
        gsum[b][c] = s;
    }
    __syncthreads();

    if (tid < 128) {
        int b = tid & 31, jl = tid >> 5;
        int j = nt * 4 + jl;
        float gi = gsum[b][jl]      + bias[j];
        float gf = gsum[b][4 + jl]  + bias[1024 + j];
        float gg = gsum[b][8 + jl]  + bias[2048 + j];
        float go = gsum[b][12 + jl] + bias[3072 + j];
        float cv = c_state[b * 1024 + j];
        float c2 = sigf(gf) * cv + sigf(gi) * tanhf(gg);
        float h2 = sigf(go) * tanhf(c2);
        c_state[b * 1024 + j] = c2;
        h_f32[b * 1024 + j]   = h2;
        h_bf16[b * 1024 + j]  = __float2bfloat16(h2);
    }
}

// ============================================================
// Q kernel: all work whose inputs are ready after attn(t).
//   [0,256)   lstmD(t)
//   [256,512) lstmA(t+1)
//   [512,544) lpm(t+1) = loc_conv+dense(align(t), awc(t)) + pm
//   [544,608) proj(t-1)
// No cross-block dependencies inside the kernel.
// ============================================================
__global__ __launch_bounds__(512, 2) void qstep_kernel(
    const __hip_bfloat16* __restrict__ x2b,
    __hip_bfloat16* __restrict__ ctxb,
    __hip_bfloat16* __restrict__ ahb0, __hip_bfloat16* __restrict__ ahb1,
    __hip_bfloat16* __restrict__ dhb0, __hip_bfloat16* __restrict__ dhb1,
    const __hip_bfloat16* __restrict__ wswA,
    const __hip_bfloat16* __restrict__ wswD,
    const float* __restrict__ a_b, const float* __restrict__ d_b,
    float* __restrict__ ac, float* __restrict__ dc,
    float* __restrict__ ahf,
    float* __restrict__ dhf0, float* __restrict__ dhf1,
    const float* __restrict__ ctxf0, const float* __restrict__ ctxf1,
    const float* __restrict__ proj_w, const float* __restrict__ proj_b,
    const float* __restrict__ gate_w, const float* __restrict__ gate_b,
    float* __restrict__ out_mel, float* __restrict__ out_gate,
    const float* __restrict__ lconv, const float* __restrict__ ldense,
    const float* __restrict__ pm,
    const float* __restrict__ awc, const float* __restrict__ align_out,
    float* __restrict__ lpmbuf,
    int t)
{
    __shared__ char smem[QSM_BYTES];
    int blk = blockIdx.x;
    int tid = threadIdx.x;

    if (blk < 256) {
        // ---------------- lstmD(t) ----------------
        if (t < 0) return;
        lstm_tile<2560, 1024, 512, 1024, 512, 1024>(
            smem, blk,
            HOLD(t, ahb0, ahb1), ctxb, HOLD(t - 1, dhb0, dhb1),
            wswD, d_b, dc,
            HOLD(t, dhf1, dhf0), HOLD(t, dhb0, dhb1));
        return;
    }

    if (blk < 512) {
        // ---------------- lstmA(t+1) ----------------
        int s = t + 1;
        if (s > 511) return;
        lstm_tile<1792, 256, 512, 256, 512, 1024>(
            smem, blk - 256,
            x2b + (size_t)s * 8192, ctxb, HOLD(s - 1, ahb0, ahb1),
            wswA, a_b, ac, ahf, HOLD(s, ahb0, ahb1));
        return;
    }

    if (blk < 544) {
        // ---------------- lpm(t+1): conv + dense + pm ----------------
        if (t + 1 > 511) return;
        int b = blk - 512;
        __hip_bfloat16 (*locb)[40] = (__hip_bfloat16(*)[40])smem;
        float* aw_s  = (float*)(smem + 20480);
        float* awc_s = (float*)(smem + 21632);

        if (tid < 288) {
            int tt = tid - 15;
            float a = 0.f, c = 0.f;
            if (tt >= 0 && tt < 256) {
                a = (t >= 0) ? align_out[(size_t)b * 131072 + (size_t)t * 256 + tt] : 0.f;
                c = awc[b * 256 + tt];
            }
            aw_s[tid] = a; awc_s[tid] = c;
        }
        __syncthreads();

        for (int it = 0; it < 2; ++it) {
            int item = tid + it * 512;
            int f = item >> 5, ttg = item & 31;
            const float* kcA = lconv + f * 62;
            const float* kcB = kcA + 31;
            float ka[31], kb_[31];
#pragma unroll
            for (int k = 0; k < 31; ++k) { ka[k] = kcA[k]; kb_[k] = kcB[k]; }
            float acc[8];
#pragma unroll
            for (int s = 0; s < 8; ++s) acc[s] = 0.f;
            int base = ttg * 8;
#pragma unroll
            for (int u = 0; u < 38; ++u) {
                float av = aw_s[base + u];
                float cv = awc_s[base + u];
#pragma unroll
                for (int s = 0; s < 8; ++s) {
                    int k = u - s;
                    if (k >= 0 && k < 31) {
                        acc[s] = fmaf(ka[k], av, acc[s]);
                        acc[s] = fmaf(kb_[k], cv, acc[s]);
                    }
                }
            }
#pragma unroll
            for (int s = 0; s < 8; ++s)
                locb[base + s][f] = __float2bfloat16(acc[s]);
        }
        __syncthreads();

        // dense via MFMA; wave w covers m-tiles 2w, 2w+1; write loc+pm (f32)
        {
            int lane = tid & 63;
            int w    = tid >> 6;
            int c    = lane & 15, q = lane >> 4;

            bf16x8 Bf[8];
#pragma unroll
            for (int tc = 0; tc < 8; ++tc) {
                int d = tc * 16 + c;
                const float* lp = ldense + d * 32 + q * 8;
                float4 f0 = *(const float4*)lp;
                float4 f1 = *(const float4*)(lp + 4);
                union { bf16x8 vv; __hip_bfloat16 h[8]; } u;
                u.h[0] = __float2bfloat16(f0.x); u.h[1] = __float2bfloat16(f0.y);
                u.h[2] = __float2bfloat16(f0.z); u.h[3] = __float2bfloat16(f0.w);
                u.h[4] = __float2bfloat16(f1.x); u.h[5] = __float2bfloat16(f1.y);
                u.h[6] = __float2bfloat16(f1.z); u.h[7] = __float2bfloat16(f1.w);
                Bf[tc] = u.vv;
            }
#pragma unroll
            for (int half = 0; half < 2; ++half) {
                int mt = w * 2 + half;
                bf16x8 Af = *(const bf16x8*)&locb[mt * 16 + c][q * 8];
                f32x4 zero = {0.f, 0.f, 0.f, 0.f};
#pragma unroll
                for (int tc = 0; tc < 8; ++tc) {
                    f32x4 P = __builtin_amdgcn_mfma_f32_16x16x32_bf16(Af, Bf[tc], zero, 0, 0, 0);
                    int d = tc * 16 + c;
#pragma unroll
                    for (int r = 0; r < 4; ++r) {
                        int ttp = mt * 16 + q * 4 + r;
                        size_t ix = ((size_t)b << 15) + (size_t)ttp * 128 + d;
                        lpmbuf[ix] = P[r] + pm[ix];
                    }
                }
            }
        }
        return;
    }

    // ---------------- proj(t-1) ----------------
    {
        if (t < 1) return;
        int pb = blk - 544;
        int b = pb >> 1, half = pb & 1;
        int tp = t - 1;
        const float* dh = HOLD(tp, dhf1, dhf0);
        const float* cx = HOLD(tp, ctxf1, ctxf0);
        float* pi = (float*)smem;
        for (int i = tid; i < 1024; i += 512) pi[i] = dh[b * 1024 + i];
        if (tid < 512) pi[1024 + tid] = cx[b * 512 + tid];
        __syncthreads();
        int w = tid >> 6, lane = tid & 63;
        int nOut = half ? 41 : 40;
        for (int o = w; o < nOut; o += 8) {
            bool isGate = (half && o == 40);
            int m = half * 40 + o;
            const float* wr = isGate ? gate_w : (proj_w + (size_t)m * 1536);
            float s = 0.f;
#pragma unroll
            for (int c = 0; c < 6; ++c) {
                float4 wv = *(const float4*)(wr + c * 256 + lane * 4);
                const float* pp = pi + c * 256 + lane * 4;
                s += wv.x * pp[0] + wv.y * pp[1] + wv.z * pp[2] + wv.w * pp[3];
            }
#pragma unroll
            for (int mm = 32; mm >= 1; mm >>= 1) s += __shfl_xor(s, mm);
            if (lane == 0) {
                if (isGate) out_gate[b * 512 + tp] = s + gate_b[0];
                else out_mel[(size_t)b * (80 * 512) + (size_t)m * 512 + tp]
                        = s + proj_b[m];
            }
        }
    }
}

// ============================================================
// P kernel: slim attention. 32 blocks x 1024 threads.
// pq -> energies (read lpm) -> single-wave softmax -> context
// ============================================================
__global__ __launch_bounds__(1024) void attn_kernel(
    const float* __restrict__ memory,
    const int*   __restrict__ mlen,
    const float* __restrict__ wq,
    const float* __restrict__ v,
    const float* __restrict__ lpmbuf,
    const float* __restrict__ ahf,
    float* __restrict__ ctxf_cur,
    __hip_bfloat16* __restrict__ ctxb,
    float* __restrict__ awc,
    float* __restrict__ align_out,
    int t)
{
    int b = blockIdx.x, tid = threadIdx.x;
    __shared__ float red[1024];
    __shared__ float pq_s[128];
    __shared__ float v_s[128];
    __shared__ float wgt_s[256];

    int len = mlen[b];

    // ---- phase A: pq partials (+ stage v) ----
    if (tid < 128) v_s[tid] = v[tid];
    {
        int d = tid >> 3, p = tid & 7;
        const float4* wr = (const float4*)(wq + (size_t)d * 1024 + p * 128);
        const float4* hr = (const float4*)(ahf + b * 1024 + p * 128);
        float s = 0.f;
#pragma unroll 8
        for (int k = 0; k < 32; ++k) {
            float4 a = wr[k], h4 = hr[k];
            s += a.x * h4.x + a.y * h4.y + a.z * h4.z + a.w * h4.w;
        }
        red[tid] = s;
    }
    __syncthreads();

    // ---- phase B: pq reduce ----
    if (tid < 128) {
        float s = 0.f;
#pragma unroll
        for (int p = 0; p < 8; ++p) s += red[tid * 8 + p];
        pq_s[tid] = s;
    }
    __syncthreads();

    // ---- phase C: energy partials; thread (tt, dg) handles 32 d ----
    {
        int ttc = tid >> 2, dg = tid & 3;
        const float4* lp4 = (const float4*)(lpmbuf + ((size_t)b << 15) + (size_t)ttc * 128 + dg * 32);
        const float4* pq4 = (const float4*)(pq_s + dg * 32);
        const float4* v4  = (const float4*)(v_s + dg * 32);
        float pe = 0.f;
#pragma unroll
        for (int j = 0; j < 8; ++j) {
            float4 x = lp4[j], pq = pq4[j], vv = v4[j];
            pe += ftanh(x.x + pq.x) * vv.x + ftanh(x.y + pq.y) * vv.y
                + ftanh(x.z + pq.z) * vv.z + ftanh(x.w + pq.w) * vv.w;
        }
        __syncthreads();          // red free for reuse
        red[tid] = pe;
    }
    __syncthreads();

    // ---- phase D: single-wave softmax + align/awc writes ----
    if (tid < 64) {
        float ev[4];
        float mx = -1e30f;
#pragma unroll
        for (int r = 0; r < 4; ++r) {
            int tt = tid * 4 + r;
            float e = red[tt * 4] + red[tt * 4 + 1] + red[tt * 4 + 2] + red[tt * 4 + 3];
            ev[r] = (tt < len) ? e : -1e9f;
            mx = fmaxf(mx, ev[r]);
        }
#pragma unroll
        for (int mm = 32; mm >= 1; mm >>= 1) mx = fmaxf(mx, __shfl_xor(mx, mm));
        float sum = 0.f;
#pragma unroll
        for (int r = 0; r < 4; ++r) {
            ev[r] = exp2f((ev[r] - mx) * 1.4426950408889634f);
            sum += ev[r];
        }
#pragma unroll
        for (int mm = 32; mm >= 1; mm >>= 1) sum += __shfl_xor(sum, mm);
        float winv = __builtin_amdgcn_rcpf(sum);
#pragma unroll
        for (int r = 0; r < 4; ++r) {
            int tt = tid * 4 + r;
            float wg = ev[r] * winv;
            wgt_s[tt] = wg;
            align_out[(size_t)b * 131072 + (size_t)t * 256 + tt] = wg;
            awc[b * 256 + tt] += wg;
        }
    }
    __syncthreads();

    // ---- phase E: context (2-way tt split, 4-way ILP) ----
    {
        int ee = tid & 511, p = tid >> 9;
        const float* mr = memory + (size_t)b * 131072 + ee;
        float s0 = 0.f, s1 = 0.f, s2 = 0.f, s3 = 0.f;
        int t0 = p * 128;
        for (int ttl = 0; ttl < 128; ttl += 4) {
            int tt = t0 + ttl;
            s0 = fmaf(wgt_s[tt],     mr[(size_t)tt * 512],       s0);
            s1 = fmaf(wgt_s[tt + 1], mr[(size_t)(tt + 1) * 512], s1);
            s2 = fmaf(wgt_s[tt + 2], mr[(size_t)(tt + 2) * 512], s2);
            s3 = fmaf(wgt_s[tt + 3], mr[(size_t)(tt + 3) * 512], s3);
        }
        red[p * 512 + ee] = (s0 + s1) + (s2 + s3);
    }
    __syncthreads();
    if (tid < 512) {
        float cv = red[tid] + red[512 + tid];
        ctxf_cur[b * 512 + tid] = cv;
        ctxb[b * 512 + tid] = __float2bfloat16(cv);
    }
}

// ============================================================
// Projection + gate (f32) — final timestep only
// ============================================================
__global__ __launch_bounds__(256) void proj_kernel(
    const float* __restrict__ dh,
    const float* __restrict__ ctx,
    const float* __restrict__ proj_w,
    const float* __restrict__ proj_b,
    const float* __restrict__ gate_w,
    const float* __restrict__ gate_b,
    float* __restrict__ out_mel,
    float* __restrict__ out_gate,
    int t)
{
    int b = blockIdx.x, tid = threadIdx.x;
    __shared__ float pi[1536];
    __shared__ float red[256];
    for (int i = tid; i < 1024; i += 256) pi[i] = dh[b * 1024 + i];
    for (int i = tid; i < 512; i += 256) pi[1024 + i] = ctx[b * 512 + i];
    __syncthreads();

    float s = 0.f;
    if (tid < 240) {
        int m = tid / 3, p = tid - m * 3;
        const float* wr = proj_w + (size_t)m * 1536 + p * 512;
        const float* pr = pi + p * 512;
        for (int k = 0; k < 512; ++k) s += wr[k] * pr[k];
    } else {
        int p = tid - 240;
        const float* wr = gate_w + p * 96;
        const float* pr = pi + p * 96;
        for (int k = 0; k < 96; ++k) s += wr[k] * pr[k];
    }
    red[tid] = s;
    __syncthreads();
    if (tid < 80) {
        float m3 = red[tid * 3] + red[tid * 3 + 1] + red[tid * 3 + 2];
        out_mel[(size_t)b * (80 * 512) + (size_t)tid * 512 + t] = m3 + proj_b[tid];
    } else if (tid == 80) {
        float g = gate_b[0];
#pragma unroll
        for (int p = 0; p < 16; ++p) g += red[240 + p];
        out_gate[b * 512 + t] = g;
    }
}

// ============================================================
extern "C" void kernel_launch(void* const* d_in, const int* in_sizes, int n_in,
                              void* d_out, int out_size, void* d_ws, size_t ws_size,
                              hipStream_t stream)
{
    const float* memory   = (const float*)d_in[0];
    const float* dec_in   = (const float*)d_in[1];
    const int*   mlen     = (const int*)  d_in[2];
    const float* pw1      = (const float*)d_in[3];
    const float* pw2      = (const float*)d_in[4];
    const float* a_wih    = (const float*)d_in[5];
    const float* a_whh    = (const float*)d_in[6];
    const float* a_b      = (const float*)d_in[7];
    const float* wq       = (const float*)d_in[8];
    const float* wm       = (const float*)d_in[9];
    const float* v        = (const float*)d_in[10];
    const float* lconv    = (const float*)d_in[11];
    const float* ldense   = (const float*)d_in[12];
    const float* d_wih    = (const float*)d_in[13];
    const float* d_whh    = (const float*)d_in[14];
    const float* d_b      = (const float*)d_in[15];
    const float* proj_w   = (const float*)d_in[16];
    const float* proj_b   = (const float*)d_in[17];
    const float* gate_w   = (const float*)d_in[18];
    const float* gate_b   = (const float*)d_in[19];

    char* ws = (char*)d_ws;
    __hip_bfloat16* x2b  = (__hip_bfloat16*)(ws + B_X2);
    float*          pm   = (float*)(ws + B_PM);
    __hip_bfloat16* wswA = (__hip_bfloat16*)(ws + B_WSA);
    __hip_bfloat16* wswD = (__hip_bfloat16*)(ws + B_WSD);
    __hip_bfloat16* ahb0 = (__hip_bfloat16*)(ws + B_AHB0);
    __hip_bfloat16* ahb1 = (__hip_bfloat16*)(ws + B_AHB1);
    __hip_bfloat16* dhb0 = (__hip_bfloat16*)(ws + B_DHB0);
    __hip_bfloat16* dhb1 = (__hip_bfloat16*)(ws + B_DHB1);
    __hip_bfloat16* ctxb = (__hip_bfloat16*)(ws + B_CTXB);
    float*          ac   = (float*)(ws + B_AC);
    float*          dc   = (float*)(ws + B_DC);
    float*          awcp = (float*)(ws + B_AWC);
    float*          ahf  = (float*)(ws + B_AHF);
    float*          dhf0 = (float*)(ws + B_DHF0);
    float*          dhf1 = (float*)(ws + B_DHF1);
    float*          ctxf0= (float*)(ws + B_CTXF0);
    float*          ctxf1= (float*)(ws + B_CTXF1);
    float*          lpmb = (float*)(ws + B_LPM);

    float* out       = (float*)d_out;
    float* out_mel   = out + OUT_MEL;
    float* out_gate  = out + OUT_GATE;
    float* out_align = out + OUT_ALIGN;

    hipMemsetAsync(ws + B_ZERO_START, 0, B_ZERO_BYTES, stream);

    prenet_kernel<<<1024, 256, 0, stream>>>(dec_in, pw1, pw2, x2b);
    pm_kernel<<<dim3(16, 32), 128, 0, stream>>>(memory, wm, pm);
    swizzle_kernel<<<3584, 256, 0, stream>>>(a_wih, 768,  a_whh, 1024, wswA, 1792);
    swizzle_kernel<<<5120, 256, 0, stream>>>(d_wih, 1536, d_whh, 1024, wswD, 2560);

    // prologue: lstmA(0) + lpm(0)   (lstmD/proj guarded out at t=-1)
    qstep_kernel<<<608, 512, 0, stream>>>(
        x2b, ctxb, ahb0, ahb1, dhb0, dhb1, wswA, wswD, a_b, d_b,
        ac, dc, ahf, dhf0, dhf1, ctxf0, ctxf1,
        proj_w, proj_b, gate_w, gate_b, out_mel, out_gate,
        lconv, ldense, pm, awcp, out_align, lpmb, -1);

    for (int t = 0; t < 512; ++t) {
        float* ctxf_cur = (t & 1) ? ctxf1 : ctxf0;

        attn_kernel<<<32, 1024, 0, stream>>>(
            memory, mlen, wq, v, lpmb, ahf,
            ctxf_cur, ctxb, awcp, out_align, t);

        qstep_kernel<<<608, 512, 0, stream>>>(
            x2b, ctxb, ahb0, ahb1, dhb0, dhb1, wswA, wswD, a_b, d_b,
            ac, dc, ahf, dhf0, dhf1, ctxf0, ctxf1,
            proj_w, proj_b, gate_w, gate_b, out_mel, out_gate,
            lconv, ldense, pm, awcp, out_align, lpmb, t);
    }

    // final projection for t=511 (odd -> dhf1/ctxf1)
    proj_kernel<<<32, 256, 0, stream>>>(
        dhf1, ctxf1, proj_w, proj_b, gate_w, gate_b,
        out_mel, out_gate, 511);
}